// Round 1
// baseline (304.526 us; speedup 1.0000x reference)
//
#include <hip/hip_runtime.h>
#include <math.h>

// ---------------- workspace layout (float offsets) ----------------
// T tables:  [0, 3632)     T1@0(2048) T2@2048(1024) T3@3072(288) T4@3360(256) T5@3616(16)
// S tables:  [3632, 3873)  S1@3632 S2@3760 S3@3824 S4@3856 S5@3872
// WT (transposed weights, [r][ci/4][co] float4):
//   WT1@4096(204800) WT2@208896(131072) WT3@339968(18432) WT4@358400(8192) WT5@366592(256)
// buf0@366848 (802816 = max(A1,A3))   buf1@1169664 (1605632 = max(A2,A4))
// total 2,775,296 floats = 11.1 MB

#define OFF_T1 0
#define OFF_T2 2048
#define OFF_T3 3072
#define OFF_T4 3360
#define OFF_T5 3616
#define OFF_S  3632
#define OFF_WT1 4096
#define OFF_WT2 208896
#define OFF_WT3 339968
#define OFF_WT4 358400
#define OFF_WT5 366592
#define OFF_BUF0 366848
#define OFF_BUF1 1169664

// prep1: (a) transpose weights into [r][ci/4][co][4] layout, (b) T[co,r] = sum_ci |w|
__global__ __launch_bounds__(256) void prep1(const float* __restrict__ w1, const float* __restrict__ w2,
                      const float* __restrict__ w3, const float* __restrict__ w4,
                      const float* __restrict__ w5, float* __restrict__ ws) {
  int idx = blockIdx.x * 256 + threadIdx.x;
  if (idx < 362752) {
    const float* W; int CIN, COUT, KK, e, wtb;
    if (idx < 204800)      { W=w1; CIN=100; COUT=128; KK=16; e=idx;        wtb=OFF_WT1; }
    else if (idx < 335872) { W=w2; CIN=128; COUT=64;  KK=16; e=idx-204800; wtb=OFF_WT2; }
    else if (idx < 354304) { W=w3; CIN=64;  COUT=32;  KK=9;  e=idx-335872; wtb=OFF_WT3; }
    else if (idx < 362496) { W=w4; CIN=32;  COUT=16;  KK=16; e=idx-354304; wtb=OFF_WT4; }
    else                   { W=w5; CIN=16;  COUT=1;   KK=16; e=idx-362496; wtb=OFF_WT5; }
    int ci = e / (COUT*KK); int rem = e % (COUT*KK); int co = rem / KK; int r = rem % KK;
    ws[wtb + ((r*(CIN/4) + (ci>>2))*COUT + co)*4 + (ci&3)] = W[e];
  }
  if (idx < 3632) {
    const float* W; int CIN, COUT, KK, local;
    if (idx < 2048)      { W=w1; CIN=100; COUT=128; KK=16; local=idx; }
    else if (idx < 3072) { W=w2; CIN=128; COUT=64;  KK=16; local=idx-2048; }
    else if (idx < 3360) { W=w3; CIN=64;  COUT=32;  KK=9;  local=idx-3072; }
    else if (idx < 3616) { W=w4; CIN=32;  COUT=16;  KK=16; local=idx-3360; }
    else                 { W=w5; CIN=16;  COUT=1;   KK=16; local=idx-3616; }
    int co = local / KK, r = local % KK;
    float s = 0.f;
    for (int ci = 0; ci < CIN; ++ci) s += fabsf(W[(ci*COUT + co)*KK + r]);
    ws[idx] = s;
  }
}

// prep2: S[co] = sum over k*k of T
__global__ __launch_bounds__(256) void prep2(float* __restrict__ ws) {
  int idx = threadIdx.x;
  if (idx >= 241) return;
  int tb, KK;
  if (idx < 128)      { tb = OFF_T1 + idx*16;       KK=16; }
  else if (idx < 192) { tb = OFF_T2 + (idx-128)*16; KK=16; }
  else if (idx < 224) { tb = OFF_T3 + (idx-192)*9;  KK=9;  }
  else if (idx < 240) { tb = OFF_T4 + (idx-224)*16; KK=16; }
  else                { tb = OFF_T5;                KK=16; }
  float s = 0.f;
  for (int r = 0; r < KK; ++r) s += ws[tb + r];
  ws[OFF_S + idx] = s;
}

// fused layer: adder conv-transpose + instance norm + relu/tanh
// one block per batch element; lanes spatial-major (idx = s*COUT + co)
template<int CIN, int COUT, int K, int STRIDE, int PAD,
         int HI, int WI, int HO, int WO, int ACT, int CP>
__global__ __launch_bounds__(256)
void layer_kernel(const float* __restrict__ X, const float* __restrict__ WT,
                  const float* __restrict__ T, const float* __restrict__ SS,
                  float* __restrict__ Y) {
  constexpr int S = HO*WO;
  constexpr int HIWI = HI*WI;
  constexpr int NIN = CIN*HIWI;
  constexpr int CIN4 = CIN/4;
  __shared__ float xst[HIWI*CIN];       // [pos][ci], ci contiguous
  __shared__ float outs[S*CP];          // [s][co] padded stride CP
  __shared__ float stat_mean[COUT], stat_rstd[COUT];
  __shared__ float wred[8];
  const int b = blockIdx.x;
  const int tid = threadIdx.x;

  for (int i = tid; i < NIN; i += 256) {
    int ci = i / HIWI, p = i % HIWI;
    xst[p*CIN + ci] = X[b*NIN + i];
  }
  __syncthreads();

  // ---- phase 1: adder conv (real taps only; structural zeros via T/S tables) ----
  for (int idx = tid; idx < COUT*S; idx += 256) {
    const int co = idx % COUT;
    const int s  = idx / COUT;
    const int oh = s / WO, ow = s % WO;
    float acc = SS[co];
    #pragma unroll
    for (int kh = 0; kh < K; ++kh) {
      const int th = oh + PAD - kh;
      if (th < 0) continue;
      if (th % STRIDE) continue;
      const int ih = th / STRIDE;
      if (ih >= HI) continue;
      #pragma unroll
      for (int kw = 0; kw < K; ++kw) {
        const int tw = ow + PAD - kw;
        if (tw < 0) continue;
        if (tw % STRIDE) continue;
        const int iw = tw / STRIDE;
        if (iw >= WI) continue;
        const int r = kh*K + kw;
        acc -= T[co*(K*K) + r];
        const float4* xp4 = reinterpret_cast<const float4*>(&xst[(ih*WI + iw)*CIN]);
        const float4* wp4 = reinterpret_cast<const float4*>(WT) + (size_t)r*CIN4*COUT + co;
        float a0=0.f, a1=0.f, a2=0.f, a3=0.f;
        #pragma unroll 2
        for (int c4 = 0; c4 < CIN4; ++c4) {
          float4 xv = xp4[c4];
          float4 wv = wp4[(size_t)c4*COUT];
          a0 += fabsf(xv.x - wv.x);
          a1 += fabsf(xv.y - wv.y);
          a2 += fabsf(xv.z - wv.z);
          a3 += fabsf(xv.w - wv.w);
        }
        acc += (a0+a1) + (a2+a3);
      }
    }
    outs[s*CP + co] = -acc;
  }
  __syncthreads();

  // ---- phase 2: per-(b,co) mean/var (two-pass for numerical safety) ----
  if constexpr (COUT == 1) {
    float p = 0.f;
    for (int s2 = tid; s2 < S; s2 += 256) p += outs[s2];
    #pragma unroll
    for (int off = 1; off < 64; off <<= 1) p += __shfl_xor(p, off, 64);
    if ((tid & 63) == 0) wred[tid >> 6] = p;
    __syncthreads();
    const float mean = (wred[0]+wred[1]+wred[2]+wred[3]) * (1.f/S);
    float q = 0.f;
    for (int s2 = tid; s2 < S; s2 += 256) { float d = outs[s2]-mean; q += d*d; }
    #pragma unroll
    for (int off = 1; off < 64; off <<= 1) q += __shfl_xor(q, off, 64);
    __syncthreads();
    if ((tid & 63) == 0) wred[tid >> 6] = q;
    __syncthreads();
    const float rstd = rsqrtf((wred[0]+wred[1]+wred[2]+wred[3]) * (1.f/S) + 1e-5f);
    if (tid == 0) { stat_mean[0] = mean; stat_rstd[0] = rstd; }
    __syncthreads();
  } else {
    constexpr int G = 256 / COUT;   // 2..16, power of two, wave-aligned groups
    const int g = tid / G;          // channel
    const int j = tid % G;
    float p = 0.f;
    for (int s2 = j; s2 < S; s2 += G) p += outs[s2*CP + g];
    #pragma unroll
    for (int off = 1; off < G; off <<= 1) p += __shfl_xor(p, off, 64);
    const float mean = p * (1.f/S);
    float q = 0.f;
    for (int s2 = j; s2 < S; s2 += G) { float d = outs[s2*CP + g] - mean; q += d*d; }
    #pragma unroll
    for (int off = 1; off < G; off <<= 1) q += __shfl_xor(q, off, 64);
    const float rstd = rsqrtf(q * (1.f/S) + 1e-5f);
    if (j == 0) { stat_mean[g] = mean; stat_rstd[g] = rstd; }
    __syncthreads();
  }

  // ---- phase 3: normalize + activation + coalesced store (channel-major) ----
  for (int idx = tid; idx < COUT*S; idx += 256) {
    const int co = idx / S;
    const int s2 = idx % S;
    float v = (outs[s2*CP + co] - stat_mean[co]) * stat_rstd[co];
    v = ACT ? tanhf(v) : fmaxf(v, 0.f);
    Y[(size_t)b*(COUT*S) + idx] = v;
  }
}

extern "C" void kernel_launch(void* const* d_in, const int* in_sizes, int n_in,
                              void* d_out, int out_size, void* d_ws, size_t ws_size,
                              hipStream_t stream) {
  const float* x  = (const float*)d_in[0];
  const float* w1 = (const float*)d_in[1];
  const float* w2 = (const float*)d_in[2];
  const float* w3 = (const float*)d_in[3];
  const float* w4 = (const float*)d_in[4];
  const float* w5 = (const float*)d_in[5];
  float* ws  = (float*)d_ws;
  float* out = (float*)d_out;

  prep1<<<1417, 256, 0, stream>>>(w1, w2, w3, w4, w5, ws);
  prep2<<<1, 256, 0, stream>>>(ws);

  float* A1 = ws + OFF_BUF0;   // 512*128*2*2
  float* A2 = ws + OFF_BUF1;   // 512*64*4*4
  float* A3 = ws + OFF_BUF0;   // 512*32*7*7   (reuses buf0)
  float* A4 = ws + OFF_BUF1;   // 512*16*14*14 (reuses buf1)

  //            CIN  COUT K  S  P  HI WI  HO WO  ACT CP
  layer_kernel<100, 128, 4, 2, 1,  1, 1,  2, 2,  0, 129><<<512,256,0,stream>>>(x,  ws+OFF_WT1, ws+OFF_T1, ws+OFF_S,       A1);
  layer_kernel<128,  64, 4, 2, 1,  2, 2,  4, 4,  0,  65><<<512,256,0,stream>>>(A1, ws+OFF_WT2, ws+OFF_T2, ws+OFF_S+128,   A2);
  layer_kernel< 64,  32, 3, 2, 1,  4, 4,  7, 7,  0,  33><<<512,256,0,stream>>>(A2, ws+OFF_WT3, ws+OFF_T3, ws+OFF_S+192,   A3);
  layer_kernel< 32,  16, 4, 2, 1,  7, 7, 14,14,  0,  17><<<512,256,0,stream>>>(A3, ws+OFF_WT4, ws+OFF_T4, ws+OFF_S+224,   A4);
  layer_kernel< 16,   1, 4, 2, 1, 14,14, 28,28,  1,   1><<<512,256,0,stream>>>(A4, ws+OFF_WT5, ws+OFF_T5, ws+OFF_S+240,   out);
}

// Round 5
// 253.787 us; speedup vs baseline: 1.1999x; 1.1999x over previous
//
#include <hip/hip_runtime.h>
#include <math.h>

#define NB 512   // batch

// ---------------- workspace layout (float offsets) ----------------
// T tables [r][co]: T1@0(2048) T2@2048(1024) T3@3072(288) T4@3360(256) T5@3616(16)
// WT [r][ci][co]:   WT1@4096(204800) WT2@208896(131072) WT3@339968(18432)
//                   WT4@358400(8192) WT5@366592(256)
// ACT region @366848 (1605632): xT then A1..A4 (each layer overwrites, dead-safe)
// Y   region @1972480 (1605632 max): conv partial sums [cs][q][co][b]
// total 3,578,112 floats = 14.3 MB
#define OFF_T1 0
#define OFF_T2 2048
#define OFF_T3 3072
#define OFF_T4 3360
#define OFF_T5 3616
#define OFF_WT1 4096
#define OFF_WT2 208896
#define OFF_WT3 339968
#define OFF_WT4 358400
#define OFF_WT5 366592
#define OFF_ACT 366848
#define OFF_Y   1972480

// ---- vector load/store helpers (static-indexed, rule #20 safe) ----
__device__ __forceinline__ void loadv(float (&d)[1], const float* p){ d[0]=*p; }
__device__ __forceinline__ void loadv(float (&d)[2], const float* p){ float2 v=*reinterpret_cast<const float2*>(p); d[0]=v.x; d[1]=v.y; }
__device__ __forceinline__ void loadv(float (&d)[4], const float* p){ float4 v=*reinterpret_cast<const float4*>(p); d[0]=v.x; d[1]=v.y; d[2]=v.z; d[3]=v.w; }
__device__ __forceinline__ void storev(float* p, const float (&d)[1]){ *p=d[0]; }
__device__ __forceinline__ void storev(float* p, const float (&d)[2]){ *reinterpret_cast<float2*>(p)=make_float2(d[0],d[1]); }
__device__ __forceinline__ void storev(float* p, const float (&d)[4]){ *reinterpret_cast<float4*>(p)=make_float4(d[0],d[1],d[2],d[3]); }

// prep1: (a) weights -> WT[r][ci][co], (b) x[b][ci] -> xT[ci][b]
__global__ __launch_bounds__(256)
void prep1(const float* __restrict__ w1, const float* __restrict__ w2,
           const float* __restrict__ w3, const float* __restrict__ w4,
           const float* __restrict__ w5, const float* __restrict__ x,
           float* __restrict__ ws) {
  int idx = blockIdx.x * 256 + threadIdx.x;
  if (idx < 362752) {
    const float* W; int CIN, COUT, KK, e, wtb;
    if (idx < 204800)      { W=w1; CIN=100; COUT=128; KK=16; e=idx;        wtb=OFF_WT1; }
    else if (idx < 335872) { W=w2; CIN=128; COUT=64;  KK=16; e=idx-204800; wtb=OFF_WT2; }
    else if (idx < 354304) { W=w3; CIN=64;  COUT=32;  KK=9;  e=idx-335872; wtb=OFF_WT3; }
    else if (idx < 362496) { W=w4; CIN=32;  COUT=16;  KK=16; e=idx-354304; wtb=OFF_WT4; }
    else                   { W=w5; CIN=16;  COUT=1;   KK=16; e=idx-362496; wtb=OFF_WT5; }
    int ci = e / (COUT*KK); int rem = e % (COUT*KK); int co = rem / KK; int r = rem % KK;
    ws[wtb + (r*CIN + ci)*COUT + co] = W[e];
  } else {
    int j = idx - 362752;           // 51200 total
    int b = j / 100, ci = j % 100;
    ws[OFF_ACT + ci*NB + b] = x[j];
  }
}

// prep2: T[r][co] = sum_ci |WT[r][ci][co]|  (reads the transposed copy: coalesced)
__global__ __launch_bounds__(256)
void prep2(float* __restrict__ ws) {
  int t = blockIdx.x * 256 + threadIdx.x;
  if (t >= 3632) return;
  int CIN, COUT, wtb, tb, local;
  if (t < 2048)      { CIN=100; COUT=128; wtb=OFF_WT1; tb=OFF_T1; local=t; }
  else if (t < 3072) { CIN=128; COUT=64;  wtb=OFF_WT2; tb=OFF_T2; local=t-2048; }
  else if (t < 3360) { CIN=64;  COUT=32;  wtb=OFF_WT3; tb=OFF_T3; local=t-3072; }
  else if (t < 3616) { CIN=32;  COUT=16;  wtb=OFF_WT4; tb=OFF_T4; local=t-3360; }
  else               { CIN=16;  COUT=1;   wtb=OFF_WT5; tb=OFF_T5; local=t-3616; }
  int r = local / COUT, co = local % COUT;
  const float* wp = ws + wtb + (r*CIN)*COUT + co;
  float s = 0.f;
  for (int ci = 0; ci < CIN; ++ci) s += fabsf(wp[ci*COUT]);
  ws[tb + local] = s;
}

// ---- conv: batch-on-lanes adder conv-transpose, writes y = sum|x-w| (+structural)
// X: [p][ci][b]; W: [r][ci][co]; T: [r][co]; Y: [cs][q][co][b]
// wave-uniform (q, co-group, cs); lanes = b. 1 wave per block.
template<int CIN,int COUT,int K,int PAD,int HI,int WI,int HO,int WO,int R_CO,int R_B,int CS>
__global__ __launch_bounds__(64)
void conv_kernel(const float* __restrict__ X, const float* __restrict__ W,
                 const float* __restrict__ T, float* __restrict__ Y) {
  constexpr int S = HO*WO, NCOG = COUT/R_CO, NBG = NB/(64*R_B), CINS = CIN/CS;
  const int wid = blockIdx.x;
  const int q   = wid % S;
  const int t1  = wid / S;
  const int cog = t1 % NCOG;
  const int t2  = t1 / NCOG;
  const int bg  = t2 % NBG;
  const int cs  = t2 / NBG;
  const int oh = q / WO, ow = q % WO;
  const int co0 = cog * R_CO;
  const int b0  = bg*(64*R_B) + (int)threadIdx.x * R_B;
  const int ci0 = cs * CINS;

  float acc[R_CO][R_B];
  #pragma unroll
  for (int rc = 0; rc < R_CO; ++rc)
    #pragma unroll
    for (int rb = 0; rb < R_B; ++rb) acc[rc][rb] = 0.f;

  // structural-zero taps contribute |0-w| -> T table; only cs==0 adds them
  if (cs == 0) {
    float init[R_CO];
    #pragma unroll
    for (int rc = 0; rc < R_CO; ++rc) init[rc] = 0.f;
    #pragma unroll
    for (int kh = 0; kh < K; ++kh) {
      #pragma unroll
      for (int kw = 0; kw < K; ++kw) {
        const int th = oh + PAD - kh, tw = ow + PAD - kw;
        const bool real = (th >= 0) && !(th & 1) && ((th >> 1) < HI)
                       && (tw >= 0) && !(tw & 1) && ((tw >> 1) < WI);
        if (!real) {
          const float* tp = T + (kh*K + kw)*COUT + co0;
          #pragma unroll
          for (int rc = 0; rc < R_CO; ++rc) init[rc] += tp[rc];
        }
      }
    }
    #pragma unroll
    for (int rc = 0; rc < R_CO; ++rc)
      #pragma unroll
      for (int rb = 0; rb < R_B; ++rb) acc[rc][rb] = init[rc];
  }

  // real taps: everything except x-loads and the accumulate is scalar
  #pragma unroll
  for (int kh = 0; kh < K; ++kh) {
    const int th = oh + PAD - kh;
    if (th < 0 || (th & 1)) continue;
    const int ih = th >> 1;
    if (ih >= HI) continue;
    #pragma unroll
    for (int kw = 0; kw < K; ++kw) {
      const int tw = ow + PAD - kw;
      if (tw < 0 || (tw & 1)) continue;
      const int iw = tw >> 1;
      if (iw >= WI) continue;
      const int r = kh*K + kw, p = ih*WI + iw;
      const float* xp = X + (p*CIN + ci0)*NB + b0;
      const float* wp = W + (r*CIN + ci0)*COUT + co0;
      #pragma unroll 4
      for (int ci = 0; ci < CINS; ++ci) {
        float xv[R_B];
        loadv(xv, xp + ci*NB);
        #pragma unroll
        for (int rc = 0; rc < R_CO; ++rc) {
          const float wv = wp[ci*COUT + rc];   // uniform -> s_load
          #pragma unroll
          for (int rb = 0; rb < R_B; ++rb)
            acc[rc][rb] += fabsf(xv[rb] - wv);
        }
      }
    }
  }

  float* yp = Y + ((cs*S + q)*COUT + co0)*NB + b0;
  #pragma unroll
  for (int rc = 0; rc < R_CO; ++rc) storev(yp + rc*NB, acc[rc]);
}

// ---- norm (layers 1-4): per-(b,co) two-pass instance norm + relu
// Y: [cs][q][co][b] partials; A: [q][co][b]
template<int COUT,int S,int CS>
__global__ __launch_bounds__(256)
void norm_kernel(const float* __restrict__ Y, float* __restrict__ A) {
  __shared__ float red[4][64];
  __shared__ float stat[2][64];
  const int co = blockIdx.x % COUT;
  const int bg = blockIdx.x / COUT;
  const int lane = threadIdx.x & 63;
  const int w = threadIdx.x >> 6;
  const int b = bg*64 + lane;
  const float* yb = Y + co*NB + b;

  float s = 0.f;
  for (int q = w; q < S; q += 4) {
    float v = 0.f;
    #pragma unroll
    for (int cs = 0; cs < CS; ++cs) v += yb[(cs*S + q)*COUT*NB];
    s += v;
  }
  red[w][lane] = s;
  __syncthreads();
  if (w == 0) stat[0][lane] = (red[0][lane]+red[1][lane]+red[2][lane]+red[3][lane]) * (1.f/S);
  __syncthreads();
  const float mu = stat[0][lane];

  float s2 = 0.f;
  for (int q = w; q < S; q += 4) {
    float v = 0.f;
    #pragma unroll
    for (int cs = 0; cs < CS; ++cs) v += yb[(cs*S + q)*COUT*NB];
    const float d = v - mu;
    s2 += d*d;
  }
  red[w][lane] = s2;
  __syncthreads();
  if (w == 0) stat[1][lane] = rsqrtf((red[0][lane]+red[1][lane]+red[2][lane]+red[3][lane]) * (1.f/S) + 1e-5f);
  __syncthreads();
  const float rs = stat[1][lane];

  for (int q = w; q < S; q += 4) {
    float v = 0.f;
    #pragma unroll
    for (int cs = 0; cs < CS; ++cs) v += yb[(cs*S + q)*COUT*NB];
    const float n = (mu - v) * rs;       // adder out = -y, norm flips sign
    A[(q*COUT + co)*NB + b] = fmaxf(n, 0.f);
  }
}

// ---- norm layer 5: COUT=1, S=784; one wave per b; writes final [b][q] + tanh
__global__ __launch_bounds__(256)
void norm5_kernel(const float* __restrict__ Y, float* __restrict__ out) {
  const int w = threadIdx.x >> 6, lane = threadIdx.x & 63;
  const int b = blockIdx.x*4 + w;
  const float* yb = Y + b;

  float s = 0.f;
  for (int q = lane; q < 784; q += 64) s += yb[q*NB];
  #pragma unroll
  for (int off = 1; off < 64; off <<= 1) s += __shfl_xor(s, off, 64);
  const float mu = s * (1.f/784.f);

  float s2 = 0.f;
  for (int q = lane; q < 784; q += 64) { float d = yb[q*NB] - mu; s2 += d*d; }
  #pragma unroll
  for (int off = 1; off < 64; off <<= 1) s2 += __shfl_xor(s2, off, 64);
  const float rs = rsqrtf(s2*(1.f/784.f) + 1e-5f);

  for (int q = lane; q < 784; q += 64) {
    const float n = (mu - yb[q*NB]) * rs;
    const float ax = fabsf(n);
    const float e = __expf(-2.f*ax);
    const float t = (1.f - e) / (1.f + e);
    out[b*784 + q] = copysignf(t, n);   // tanh(n)
  }
}

extern "C" void kernel_launch(void* const* d_in, const int* in_sizes, int n_in,
                              void* d_out, int out_size, void* d_ws, size_t ws_size,
                              hipStream_t stream) {
  const float* x  = (const float*)d_in[0];
  const float* w1 = (const float*)d_in[1];
  const float* w2 = (const float*)d_in[2];
  const float* w3 = (const float*)d_in[3];
  const float* w4 = (const float*)d_in[4];
  const float* w5 = (const float*)d_in[5];
  float* ws  = (float*)d_ws;
  float* out = (float*)d_out;

  float* ACT = ws + OFF_ACT;
  float* Y   = ws + OFF_Y;

  prep1<<<1617, 256, 0, stream>>>(w1, w2, w3, w4, w5, x, ws);
  prep2<<<15, 256, 0, stream>>>(ws);

  // conv<CIN,COUT,K,PAD,HI,WI,HO,WO,R_CO,R_B,CS>   grid = S*NCOG*NBG*CS (1 wave/block)
  conv_kernel<100,128,4,1,  1, 1,  2, 2, 4,2,1><<< 512,64,0,stream>>>(ACT, ws+OFF_WT1, ws+OFF_T1, Y);
  norm_kernel<128,  4,1><<<1024,256,0,stream>>>(Y, ACT);

  conv_kernel<128, 64,4,1,  2, 2,  4, 4, 4,2,2><<<2048,64,0,stream>>>(ACT, ws+OFF_WT2, ws+OFF_T2, Y);
  norm_kernel< 64, 16,2><<< 512,256,0,stream>>>(Y, ACT);

  conv_kernel< 64, 32,3,1,  4, 4,  7, 7, 4,2,2><<<3136,64,0,stream>>>(ACT, ws+OFF_WT3, ws+OFF_T3, Y);
  norm_kernel< 32, 49,2><<< 256,256,0,stream>>>(Y, ACT);

  conv_kernel< 32, 16,4,1,  7, 7, 14,14, 4,2,1><<<3136,64,0,stream>>>(ACT, ws+OFF_WT4, ws+OFF_T4, Y);
  norm_kernel< 16,196,1><<< 128,256,0,stream>>>(Y, ACT);

  conv_kernel< 16,  1,4,1, 14,14, 28,28, 1,4,1><<<1568,64,0,stream>>>(ACT, ws+OFF_WT5, ws+OFF_T5, Y);
  norm5_kernel<<<128,256,0,stream>>>(Y, out);
}